// Round 1
// baseline (3502.431 us; speedup 1.0000x reference)
//
#include <hip/hip_runtime.h>

#define H 128
#define CD 64
#define P 4            // points per wave
#define WAVES 4        // waves per block
#define PPB (P*WAVES)  // 16 points per block
#define DT_MAXF 0.125f
#define NSTEPS 8

// tanh(x) = 1 - 2/(exp(2x)+1), via hw exp2 + rcp (~1e-6 abs err, fine vs 0.1 threshold)
__device__ __forceinline__ float fast_tanh(float x) {
    float e = __builtin_amdgcn_exp2f(x * 2.8853900817779268f); // 2*log2(e)
    float r = __builtin_amdgcn_rcpf(e + 1.0f);
    return 1.0f - 2.0f * r;
}

__device__ __forceinline__ float f4c(const float4& v, int kk) {
    switch (kk) { case 0: return v.x; case 1: return v.y; case 2: return v.z; default: return v.w; }
}

__global__ __launch_bounds__(256, 2)
void velwarp(const float* __restrict__ code, const float* __restrict__ pos,
             const float* __restrict__ t1g, const float* __restrict__ t2g,
             const float* __restrict__ W1, const float* __restrict__ b1,
             const float* __restrict__ W2, const float* __restrict__ b2,
             const float* __restrict__ W3, const float* __restrict__ b3,
             float* __restrict__ out, int N)
{
    // 64K (W2, also reused for W1[:64] during base1) + 2K + 2K + 0.5K + 8K = ~78.3 KB -> 2 blocks/CU
    __shared__ __align__(16) float Wbig[H*H];
    __shared__ __align__(16) float W1xT[H*4];   // W1xT[k][i] = W1[64+i][k]
    __shared__ __align__(16) float W3s[H*4];    // W3s[u][o], o<3 (o==3 pad=0)
    __shared__ __align__(16) float b2s[H];
    __shared__ __align__(16) float h1s[WAVES][P*H]; // per-wave h1 buffer / code staging

    const int tid  = threadIdx.x;
    const int w    = tid >> 6;
    const int lane = tid & 63;
    const int u0   = lane*2, u1 = lane*2 + 1;
    const int base_n = blockIdx.x * PPB + w * P;
    float* h1w = h1s[w];

    // ---- small weight tables
    for (int idx = tid; idx < H*4; idx += 256) {
        int k = idx >> 2, i = idx & 3;
        W1xT[idx] = W1[(CD + i)*H + k];
    }
    for (int idx = tid; idx < H*4; idx += 256) {
        int u = idx >> 2, o = idx & 3;
        W3s[idx] = (o < 3) ? W3[u*3 + o] : 0.0f;
    }
    if (tid < H) b2s[tid] = b2[tid];

    // ---- W1[:64][:] -> Wbig (first 32 KB)
    {
        const float4* s4 = (const float4*)W1;
        float4* d4 = (float4*)Wbig;
        for (int i = tid; i < (CD*H)/4; i += 256) d4[i] = s4[i];
    }
    // ---- stage this wave's 4 code rows into h1w (flat [P*CD] = 256 floats)
    {
        const float4* s4 = (const float4*)(code + (size_t)base_n * CD);
        float4* d4 = (float4*)h1w;
        d4[lane] = s4[lane];
    }
    __syncthreads();

    // ---- base1[p][u] = b1[u] + code[p] @ W1[:64,u]   (constant across all steps/evals)
    float base_a[P], base_b[P];
    {
        float2 bb = *(const float2*)&b1[u0];
        #pragma unroll
        for (int p = 0; p < P; ++p) { base_a[p] = bb.x; base_b[p] = bb.y; }
        for (int i = 0; i < CD; ++i) {
            float2 wv = *(const float2*)&Wbig[i*H + u0];
            #pragma unroll
            for (int p = 0; p < P; ++p) {
                float c = h1w[p*CD + i];
                base_a[p] = fmaf(c, wv.x, base_a[p]);
                base_b[p] = fmaf(c, wv.y, base_b[p]);
            }
        }
    }
    __syncthreads();
    // ---- W2 -> Wbig
    {
        const float4* s4 = (const float4*)W2;
        float4* d4 = (float4*)Wbig;
        for (int i = tid; i < (H*H)/4; i += 256) d4[i] = s4[i];
    }
    __syncthreads();

    // ---- per-point state (replicated across all 64 lanes of the wave)
    float px[P], py[P], pz[P], tc[P], off[P], def[P][9];
    #pragma unroll
    for (int p = 0; p < P; ++p) {
        int n = base_n + p;
        px[p] = pos[n*3+0]; py[p] = pos[n*3+1]; pz[p] = pos[n*3+2];
        tc[p]  = t1g[n];
        off[p] = t1g[n] - t2g[n];
        #pragma unroll
        for (int j = 0; j < 9; ++j) def[p][j] = 0.0f;
        def[p][0] = def[p][4] = def[p][8] = 1.0f;
    }
    const float b30 = b3[0], b31 = b3[1], b32 = b3[2];
    const float4 wxa = ((const float4*)W1xT)[u0];  // W1[64..67][u0]
    const float4 wxb = ((const float4*)W1xT)[u1];
    const float4 w3a = ((const float4*)W3s)[u0];   // W3[u0][0..2]
    const float4 w3b = ((const float4*)W3s)[u1];
    const float bb2a = b2s[u0], bb2b = b2s[u1];

    for (int step = 0; step < NSTEPS; ++step) {
        float dt[P], mx[P], my[P], mz[P], tm[P];

        // ======== phase A: h1 at (xyz, t) ========
        {
            float h1a[P], h1b[P];
            #pragma unroll
            for (int p = 0; p < P; ++p) {
                float a = fabsf(off[p]);
                dt[p] = copysignf(fminf(a, DT_MAXF), off[p]);
                float za = base_a[p] + px[p]*wxa.x + py[p]*wxa.y + pz[p]*wxa.z + tc[p]*wxa.w;
                float zb = base_b[p] + px[p]*wxb.x + py[p]*wxb.y + pz[p]*wxb.z + tc[p]*wxb.w;
                h1a[p] = fast_tanh(za);
                h1b[p] = fast_tanh(zb);
            }
            __syncthreads();
            #pragma unroll
            for (int p = 0; p < P; ++p)
                *(float2*)&h1w[p*H + u0] = make_float2(h1a[p], h1b[p]);
            __syncthreads();
        }
        // ======== phase A: layer2 + v0 -> midpoint ========
        {
            float acc0[P], acc1[P];
            #pragma unroll
            for (int p = 0; p < P; ++p) { acc0[p] = bb2a; acc1[p] = bb2b; }
            for (int k = 0; k < H; k += 4) {
                float4 hv[P];
                #pragma unroll
                for (int p = 0; p < P; ++p) hv[p] = *(const float4*)&h1w[p*H + k];
                #pragma unroll
                for (int kk = 0; kk < 4; ++kk) {
                    float2 w2 = *(const float2*)&Wbig[(k+kk)*H + u0];
                    #pragma unroll
                    for (int p = 0; p < P; ++p) {
                        float h = f4c(hv[p], kk);
                        acc0[p] = fmaf(h, w2.x, acc0[p]);
                        acc1[p] = fmaf(h, w2.y, acc1[p]);
                    }
                }
            }
            #pragma unroll
            for (int p = 0; p < P; ++p) {
                float h2a = fast_tanh(acc0[p]);
                float h2b = fast_tanh(acc1[p]);
                float sx = h2a*w3a.x + h2b*w3b.x;
                float sy = h2a*w3a.y + h2b*w3b.y;
                float sz = h2a*w3a.z + h2b*w3b.z;
                #pragma unroll
                for (int m = 1; m < 64; m <<= 1) {
                    sx += __shfl_xor(sx, m, 64);
                    sy += __shfl_xor(sy, m, 64);
                    sz += __shfl_xor(sz, m, 64);
                }
                float hd = 0.5f * dt[p];
                mx[p] = px[p] - hd*(sx + b30);
                my[p] = py[p] - hd*(sy + b31);
                mz[p] = pz[p] - hd*(sz + b32);
                tm[p] = tc[p] - hd;
            }
        }
        // ======== phase B: h1 at midpoint ========
        {
            float h1a[P], h1b[P];
            #pragma unroll
            for (int p = 0; p < P; ++p) {
                float za = base_a[p] + mx[p]*wxa.x + my[p]*wxa.y + mz[p]*wxa.z + tm[p]*wxa.w;
                float zb = base_b[p] + mx[p]*wxb.x + my[p]*wxb.y + mz[p]*wxb.z + tm[p]*wxb.w;
                h1a[p] = fast_tanh(za);
                h1b[p] = fast_tanh(zb);
            }
            __syncthreads();
            #pragma unroll
            for (int p = 0; p < P; ++p)
                *(float2*)&h1w[p*H + u0] = make_float2(h1a[p], h1b[p]);
            __syncthreads();
        }
        // ======== phase B: fused layer2 + 3 forward-mode tangents ========
        // dh1_i[k] = (1-h1[k]^2) * W1[64+i][k]; shares every W2 read with the h2 pass.
        {
            float a2a[P], a2b[P];
            float dA[3][P], dB[3][P];
            #pragma unroll
            for (int p = 0; p < P; ++p) {
                a2a[p] = bb2a; a2b[p] = bb2b;
                dA[0][p]=dA[1][p]=dA[2][p]=0.f;
                dB[0][p]=dB[1][p]=dB[2][p]=0.f;
            }
            for (int k = 0; k < H; k += 4) {
                float4 hv[P];
                #pragma unroll
                for (int p = 0; p < P; ++p) hv[p] = *(const float4*)&h1w[p*H + k];
                #pragma unroll
                for (int kk = 0; kk < 4; ++kk) {
                    float2 w2 = *(const float2*)&Wbig[(k+kk)*H + u0];
                    float4 tk = ((const float4*)W1xT)[k+kk];   // broadcast, W1[64..66][k]
                    #pragma unroll
                    for (int p = 0; p < P; ++p) {
                        float h = f4c(hv[p], kk);
                        float s = fmaf(-h, h, 1.0f);
                        a2a[p] = fmaf(h, w2.x, a2a[p]);
                        a2b[p] = fmaf(h, w2.y, a2b[p]);
                        float d0 = s*tk.x, d1 = s*tk.y, d2 = s*tk.z;
                        dA[0][p] = fmaf(d0, w2.x, dA[0][p]);
                        dB[0][p] = fmaf(d0, w2.y, dB[0][p]);
                        dA[1][p] = fmaf(d1, w2.x, dA[1][p]);
                        dB[1][p] = fmaf(d1, w2.y, dB[1][p]);
                        dA[2][p] = fmaf(d2, w2.x, dA[2][p]);
                        dB[2][p] = fmaf(d2, w2.y, dB[2][p]);
                    }
                }
            }
            // reductions: vel[3] + J[3][3] per point, then state update
            #pragma unroll
            for (int p = 0; p < P; ++p) {
                float h2a = fast_tanh(a2a[p]);
                float h2b = fast_tanh(a2b[p]);
                float s2a = fmaf(-h2a, h2a, 1.0f);
                float s2b = fmaf(-h2b, h2b, 1.0f);
                float r[12];
                r[0] = h2a*w3a.x + h2b*w3b.x;
                r[1] = h2a*w3a.y + h2b*w3b.y;
                r[2] = h2a*w3a.z + h2b*w3b.z;
                #pragma unroll
                for (int i = 0; i < 3; ++i) {
                    float da  = s2a * dA[i][p];   // dh2_i[u0]
                    float db_ = s2b * dB[i][p];   // dh2_i[u1]
                    r[3 + 0*3 + i] = da*w3a.x + db_*w3b.x;  // J[0][i]
                    r[3 + 1*3 + i] = da*w3a.y + db_*w3b.y;  // J[1][i]
                    r[3 + 2*3 + i] = da*w3a.z + db_*w3b.z;  // J[2][i]
                }
                #pragma unroll
                for (int m = 1; m < 64; m <<= 1) {
                    #pragma unroll
                    for (int j = 0; j < 12; ++j) r[j] += __shfl_xor(r[j], m, 64);
                }
                float velx = r[0] + b30, vely = r[1] + b31, velz = r[2] + b32;
                float nd[9];
                #pragma unroll
                for (int o = 0; o < 3; ++o) {
                    #pragma unroll
                    for (int c = 0; c < 3; ++c) {
                        float drot = r[3+o*3+0]*def[p][0*3+c]
                                   + r[3+o*3+1]*def[p][1*3+c]
                                   + r[3+o*3+2]*def[p][2*3+c];
                        nd[o*3+c] = def[p][o*3+c] - dt[p]*drot;
                    }
                }
                #pragma unroll
                for (int j = 0; j < 9; ++j) def[p][j] = nd[j];
                px[p] -= dt[p]*velx;
                py[p] -= dt[p]*vely;
                pz[p] -= dt[p]*velz;
                tc[p]  -= dt[p];
                off[p] -= dt[p];
            }
        }
    }

    // ---- epilogue: lane p writes point p (all lanes hold identical state)
    #pragma unroll
    for (int p = 0; p < P; ++p) {
        if (lane == p) {
            int n = base_n + p;
            out[n*3+0] = px[p]; out[n*3+1] = py[p]; out[n*3+2] = pz[p];
            float* o9 = out + (size_t)N*3 + (size_t)n*9;
            #pragma unroll
            for (int j = 0; j < 9; ++j) o9[j] = def[p][j];
        }
    }
}

extern "C" void kernel_launch(void* const* d_in, const int* in_sizes, int n_in,
                              void* d_out, int out_size, void* d_ws, size_t ws_size,
                              hipStream_t stream) {
    const float* code = (const float*)d_in[0];
    const float* pos  = (const float*)d_in[1];
    const float* t1   = (const float*)d_in[2];
    const float* t2   = (const float*)d_in[3];
    const float* W1   = (const float*)d_in[4];
    const float* b1   = (const float*)d_in[5];
    const float* W2   = (const float*)d_in[6];
    const float* b2   = (const float*)d_in[7];
    const float* W3   = (const float*)d_in[8];
    const float* b3   = (const float*)d_in[9];
    float* out = (float*)d_out;
    const int N = in_sizes[1] / 3;       // 131072
    const int blocks = N / PPB;          // 8192
    velwarp<<<blocks, 256, 0, stream>>>(code, pos, t1, t2, W1, b1, W2, b2, W3, b3, out, N);
}

// Round 2
// 609.374 us; speedup vs baseline: 5.7476x; 5.7476x over previous
//
#include <hip/hip_runtime.h>

#define H 128
#define NSTEPS 8
#define DT_MAXF 0.125f
#define WAVES 4
#define PPW 16            // points per wave (one 16x16 MFMA M-tile)
#define PPB (WAVES*PPW)   // 64 points per block

typedef __attribute__((ext_vector_type(8))) short short8;   // 8 bf16 (4 VGPRs) MFMA A/B frag
typedef __attribute__((ext_vector_type(4))) float floatx4;  // MFMA C/D frag

__device__ __forceinline__ float fast_tanh(float x) {
    float e = __builtin_amdgcn_exp2f(x * 2.8853900817779268f); // 2*log2(e)
    float r = __builtin_amdgcn_rcpf(e + 1.0f);
    return 1.0f - 2.0f * r;
}
__device__ __forceinline__ unsigned f2bf(float x) {           // fp32 -> bf16 bits, RNE
    unsigned u = __float_as_uint(x);
    return (u + 0x7FFFu + ((u >> 16) & 1u)) >> 16;
}
__device__ __forceinline__ short8 pack_bf8(const float* z) {
    union { unsigned u[4]; short8 s; } U;
    #pragma unroll
    for (int j2 = 0; j2 < 4; ++j2)
        U.u[j2] = f2bf(z[2*j2]) | (f2bf(z[2*j2+1]) << 16);
    return U.s;
}

__global__ __launch_bounds__(256, 2)
void velwarp(const float* __restrict__ code, const float* __restrict__ pos,
             const float* __restrict__ t1g, const float* __restrict__ t2g,
             const float* __restrict__ W1, const float* __restrict__ b1,
             const float* __restrict__ W2, const float* __restrict__ b2,
             const float* __restrict__ W3, const float* __restrict__ b3,
             float* __restrict__ out, int N)
{
    // LDS: 32K (W1 fp32 during init, then W2 bf16 fragment-linear) + small tables = ~41.5KB
    __shared__ __align__(16) unsigned Wbuf[H*H/2];      // 32KB
    __shared__ __align__(16) float W1xc[4][H];          // W1xc[c][u] = W1[64+c][u]
    __shared__ __align__(16) float W3s[H][4];           // [u][o], o==3 pad
    __shared__ float b2s[H];
    __shared__ __align__(16) float x4[WAVES][PPW][4];   // per-wave xyzt of each point
    __shared__ __align__(16) float defS[WAVES][PPW][12];// deform 3x3 (pad to 12)

    const int tid = threadIdx.x;
    const int w   = tid >> 6;
    const int L   = tid & 63;
    const int m   = L & 15;      // point row for z1-prep; also C/D col-in-tile
    const int q   = L >> 4;      // k-quad for A/B frags; C/D row group = q*4+r
    const int pb  = blockIdx.x * PPB + w * PPW;
    const int r_  = L & 15;      // writer row when < 4

    // ---- stage W1 rows [0:64) as fp32 into Wbuf; small tables
    {
        const float4* s4 = (const float4*)W1;
        float4* d4 = (float4*)Wbuf;
        #pragma unroll 4
        for (int i = tid; i < (64*H)/4; i += 256) d4[i] = s4[i];
    }
    for (int idx = tid; idx < 4*H; idx += 256) {
        int c = idx >> 7, u = idx & (H-1);
        W1xc[c][u] = W1[(64 + c)*H + u];
    }
    for (int idx = tid; idx < 4*H; idx += 256) {
        int u = idx >> 2, o = idx & 3;
        W3s[u][o] = (o < 3) ? W3[u*3 + o] : 0.0f;
    }
    if (tid < H) b2s[tid] = b2[tid];
    __syncthreads();

    // ---- base1[s][j] = b1[u] + code[pm] . W1[:64, u],  u = s*32 + q*8 + j (lane's a-frag u-set)
    float base1[4][8];
    {
        #pragma unroll
        for (int s = 0; s < 4; ++s) {
            float4 ba = *(const float4*)&b1[s*32 + q*8];
            float4 bb = *(const float4*)&b1[s*32 + q*8 + 4];
            base1[s][0]=ba.x; base1[s][1]=ba.y; base1[s][2]=ba.z; base1[s][3]=ba.w;
            base1[s][4]=bb.x; base1[s][5]=bb.y; base1[s][6]=bb.z; base1[s][7]=bb.w;
        }
        const float* Ws = (const float*)Wbuf;
        const float* crow = code + (size_t)(pb + m) * 64;
        for (int i = 0; i < 64; ++i) {
            float c = crow[i];
            #pragma unroll
            for (int s = 0; s < 4; ++s) {
                const float* wr = &Ws[i*H + s*32 + q*8];
                float4 wa = *(const float4*)wr;
                float4 wb = *(const float4*)(wr + 4);
                base1[s][0] = fmaf(c, wa.x, base1[s][0]);
                base1[s][1] = fmaf(c, wa.y, base1[s][1]);
                base1[s][2] = fmaf(c, wa.z, base1[s][2]);
                base1[s][3] = fmaf(c, wa.w, base1[s][3]);
                base1[s][4] = fmaf(c, wb.x, base1[s][4]);
                base1[s][5] = fmaf(c, wb.y, base1[s][5]);
                base1[s][6] = fmaf(c, wb.z, base1[s][6]);
                base1[s][7] = fmaf(c, wb.w, base1[s][7]);
            }
        }
    }
    __syncthreads();

    // ---- pack W2 -> bf16 fragment-linear: chunk ch=(t*4+s)*64+lane holds
    //      B[k = s*32+(lane>>4)*8+j][n = t*16+(lane&15)], j=0..7
    for (int ch = tid; ch < 2048; ch += 256) {
        int ln = ch & 63, ts = ch >> 6;
        int s = ts & 3, t = ts >> 2;
        int k0 = s*32 + (ln >> 4)*8, n = t*16 + (ln & 15);
        unsigned pk0 = f2bf(W2[(k0+0)*H + n]) | (f2bf(W2[(k0+1)*H + n]) << 16);
        unsigned pk1 = f2bf(W2[(k0+2)*H + n]) | (f2bf(W2[(k0+3)*H + n]) << 16);
        unsigned pk2 = f2bf(W2[(k0+4)*H + n]) | (f2bf(W2[(k0+5)*H + n]) << 16);
        unsigned pk3 = f2bf(W2[(k0+6)*H + n]) | (f2bf(W2[(k0+7)*H + n]) << 16);
        ((uint4*)Wbuf)[ch] = make_uint4(pk0, pk1, pk2, pk3);
    }

    // ---- per-lane state: rows q*4+r (replicated across the 16 lanes of a quad)
    float px[4], py[4], pz[4], tc[4], off[4], dtv[4];
    #pragma unroll
    for (int r = 0; r < 4; ++r) {
        int p = pb + q*4 + r;
        px[r] = pos[p*3+0]; py[r] = pos[p*3+1]; pz[r] = pos[p*3+2];
        float t1v = t1g[p];
        tc[r] = t1v; off[r] = t1v - t2g[p];
    }
    if (r_ < 4) {
        int mm = q*4 + r_;
        *(float4*)&x4[w][mm][0] = make_float4(px[r_], py[r_], pz[r_], tc[r_]);
        #pragma unroll
        for (int j = 0; j < 9; ++j) defS[w][mm][j] = (j==0||j==4||j==8) ? 1.0f : 0.0f;
    }
    const float b30 = b3[0], b31 = b3[1], b32 = b3[2];
    __syncthreads();

    const short8* Bf = (const short8*)Wbuf;

    for (int step = 0; step < NSTEPS; ++step) {
        #pragma unroll
        for (int r = 0; r < 4; ++r)
            dtv[r] = copysignf(fminf(fabsf(off[r]), DT_MAXF), off[r]);

        // ======== eval A: h1 a-frags built directly in registers ========
        short8 af[4];
        {
            float4 xt = *(const float4*)&x4[w][m][0];
            #pragma unroll
            for (int s = 0; s < 4; ++s) {
                const int u0 = s*32 + q*8;
                float wx[8], wy[8], wz[8], wt[8], h[8];
                *(float4*)&wx[0] = *(const float4*)&W1xc[0][u0]; *(float4*)&wx[4] = *(const float4*)&W1xc[0][u0+4];
                *(float4*)&wy[0] = *(const float4*)&W1xc[1][u0]; *(float4*)&wy[4] = *(const float4*)&W1xc[1][u0+4];
                *(float4*)&wz[0] = *(const float4*)&W1xc[2][u0]; *(float4*)&wz[4] = *(const float4*)&W1xc[2][u0+4];
                *(float4*)&wt[0] = *(const float4*)&W1xc[3][u0]; *(float4*)&wt[4] = *(const float4*)&W1xc[3][u0+4];
                #pragma unroll
                for (int j = 0; j < 8; ++j) {
                    float zz = base1[s][j];
                    zz = fmaf(xt.x, wx[j], zz);
                    zz = fmaf(xt.y, wy[j], zz);
                    zz = fmaf(xt.z, wz[j], zz);
                    zz = fmaf(xt.w, wt[j], zz);
                    h[j] = fast_tanh(zz);
                }
                af[s] = pack_bf8(h);
            }
        }
        float velp[3][4];
        #pragma unroll
        for (int o = 0; o < 3; ++o)
            #pragma unroll
            for (int r = 0; r < 4; ++r) velp[o][r] = 0.0f;
        #pragma unroll
        for (int t = 0; t < 8; ++t) {
            floatx4 acc = {0.0f, 0.0f, 0.0f, 0.0f};
            #pragma unroll
            for (int s = 0; s < 4; ++s)
                acc = __builtin_amdgcn_mfma_f32_16x16x32_bf16(af[s], Bf[(t*4+s)*64 + L], acc, 0, 0, 0);
            float b2n = b2s[t*16 + m];
            float4 w3 = *(const float4*)&W3s[t*16 + m][0];
            #pragma unroll
            for (int r = 0; r < 4; ++r) {
                float h2 = fast_tanh(acc[r] + b2n);
                velp[0][r] = fmaf(h2, w3.x, velp[0][r]);
                velp[1][r] = fmaf(h2, w3.y, velp[1][r]);
                velp[2][r] = fmaf(h2, w3.z, velp[2][r]);
            }
        }
        #pragma unroll
        for (int mk = 1; mk < 16; mk <<= 1) {
            #pragma unroll
            for (int o = 0; o < 3; ++o)
                #pragma unroll
                for (int r = 0; r < 4; ++r)
                    velp[o][r] += __shfl_xor(velp[o][r], mk, 64);
        }
        // midpoint -> x4
        if (r_ < 4) {
            float hd = 0.5f * dtv[r_];
            float mmx = px[r_] - hd*(velp[0][r_] + b30);
            float mmy = py[r_] - hd*(velp[1][r_] + b31);
            float mmz = pz[r_] - hd*(velp[2][r_] + b32);
            *(float4*)&x4[w][q*4 + r_][0] = make_float4(mmx, mmy, mmz, tc[r_] - hd);
        }
        asm volatile("s_waitcnt lgkmcnt(0)" ::: "memory");

        // ======== eval B: h1 + 3 tangent a-frags in registers ========
        short8 afB[4], df[3][4];
        {
            float4 xt = *(const float4*)&x4[w][m][0];
            #pragma unroll
            for (int s = 0; s < 4; ++s) {
                const int u0 = s*32 + q*8;
                float wx[8], wy[8], wz[8], wt[8], h[8], d0[8], d1[8], d2[8];
                *(float4*)&wx[0] = *(const float4*)&W1xc[0][u0]; *(float4*)&wx[4] = *(const float4*)&W1xc[0][u0+4];
                *(float4*)&wy[0] = *(const float4*)&W1xc[1][u0]; *(float4*)&wy[4] = *(const float4*)&W1xc[1][u0+4];
                *(float4*)&wz[0] = *(const float4*)&W1xc[2][u0]; *(float4*)&wz[4] = *(const float4*)&W1xc[2][u0+4];
                *(float4*)&wt[0] = *(const float4*)&W1xc[3][u0]; *(float4*)&wt[4] = *(const float4*)&W1xc[3][u0+4];
                #pragma unroll
                for (int j = 0; j < 8; ++j) {
                    float zz = base1[s][j];
                    zz = fmaf(xt.x, wx[j], zz);
                    zz = fmaf(xt.y, wy[j], zz);
                    zz = fmaf(xt.z, wz[j], zz);
                    zz = fmaf(xt.w, wt[j], zz);
                    float hh = fast_tanh(zz);
                    float sd = fmaf(-hh, hh, 1.0f);
                    h[j] = hh;
                    d0[j] = sd * wx[j];
                    d1[j] = sd * wy[j];
                    d2[j] = sd * wz[j];
                }
                afB[s]   = pack_bf8(h);
                df[0][s] = pack_bf8(d0);
                df[1][s] = pack_bf8(d1);
                df[2][s] = pack_bf8(d2);
            }
        }
        float velq[3][4], Jp[9][4];   // Jp[o*3+i][r]
        #pragma unroll
        for (int r = 0; r < 4; ++r) {
            velq[0][r] = velq[1][r] = velq[2][r] = 0.0f;
            #pragma unroll
            for (int oi = 0; oi < 9; ++oi) Jp[oi][r] = 0.0f;
        }
        #pragma unroll
        for (int t = 0; t < 8; ++t) {
            floatx4 a0 = {0.f,0.f,0.f,0.f}, a1 = {0.f,0.f,0.f,0.f};
            floatx4 a2 = {0.f,0.f,0.f,0.f}, a3 = {0.f,0.f,0.f,0.f};
            #pragma unroll
            for (int s = 0; s < 4; ++s) {
                short8 b = Bf[(t*4+s)*64 + L];
                a0 = __builtin_amdgcn_mfma_f32_16x16x32_bf16(afB[s],  b, a0, 0, 0, 0);
                a1 = __builtin_amdgcn_mfma_f32_16x16x32_bf16(df[0][s], b, a1, 0, 0, 0);
                a2 = __builtin_amdgcn_mfma_f32_16x16x32_bf16(df[1][s], b, a2, 0, 0, 0);
                a3 = __builtin_amdgcn_mfma_f32_16x16x32_bf16(df[2][s], b, a3, 0, 0, 0);
            }
            float b2n = b2s[t*16 + m];
            float4 w3 = *(const float4*)&W3s[t*16 + m][0];
            #pragma unroll
            for (int r = 0; r < 4; ++r) {
                float h2 = fast_tanh(a0[r] + b2n);
                float s2 = fmaf(-h2, h2, 1.0f);
                velq[0][r] = fmaf(h2, w3.x, velq[0][r]);
                velq[1][r] = fmaf(h2, w3.y, velq[1][r]);
                velq[2][r] = fmaf(h2, w3.z, velq[2][r]);
                float dd0 = s2*a1[r], dd1 = s2*a2[r], dd2 = s2*a3[r];
                Jp[0][r] = fmaf(dd0, w3.x, Jp[0][r]);
                Jp[1][r] = fmaf(dd1, w3.x, Jp[1][r]);
                Jp[2][r] = fmaf(dd2, w3.x, Jp[2][r]);
                Jp[3][r] = fmaf(dd0, w3.y, Jp[3][r]);
                Jp[4][r] = fmaf(dd1, w3.y, Jp[4][r]);
                Jp[5][r] = fmaf(dd2, w3.y, Jp[5][r]);
                Jp[6][r] = fmaf(dd0, w3.z, Jp[6][r]);
                Jp[7][r] = fmaf(dd1, w3.z, Jp[7][r]);
                Jp[8][r] = fmaf(dd2, w3.z, Jp[8][r]);
            }
        }
        #pragma unroll
        for (int mk = 1; mk < 16; mk <<= 1) {
            #pragma unroll
            for (int r = 0; r < 4; ++r) {
                velq[0][r] += __shfl_xor(velq[0][r], mk, 64);
                velq[1][r] += __shfl_xor(velq[1][r], mk, 64);
                velq[2][r] += __shfl_xor(velq[2][r], mk, 64);
                #pragma unroll
                for (int oi = 0; oi < 9; ++oi)
                    Jp[oi][r] += __shfl_xor(Jp[oi][r], mk, 64);
            }
        }
        // state update (replicated; exact across lanes)
        #pragma unroll
        for (int r = 0; r < 4; ++r) {
            px[r] = fmaf(-dtv[r], velq[0][r] + b30, px[r]);
            py[r] = fmaf(-dtv[r], velq[1][r] + b31, py[r]);
            pz[r] = fmaf(-dtv[r], velq[2][r] + b32, pz[r]);
            tc[r]  -= dtv[r];
            off[r] -= dtv[r];
        }
        // deform update + next-step x4 (writer lanes only)
        if (r_ < 4) {
            int mm = q*4 + r_;
            float D[9], J[9], nd[9];
            #pragma unroll
            for (int j = 0; j < 9; ++j) D[j] = defS[w][mm][j];
            #pragma unroll
            for (int oi = 0; oi < 9; ++oi) J[oi] = Jp[oi][r_];
            #pragma unroll
            for (int o = 0; o < 3; ++o)
                #pragma unroll
                for (int c = 0; c < 3; ++c)
                    nd[o*3+c] = D[o*3+c] - dtv[r_]*(J[o*3+0]*D[0*3+c] + J[o*3+1]*D[1*3+c] + J[o*3+2]*D[2*3+c]);
            #pragma unroll
            for (int j = 0; j < 9; ++j) defS[w][mm][j] = nd[j];
            *(float4*)&x4[w][mm][0] = make_float4(px[r_], py[r_], pz[r_], tc[r_]);
        }
        asm volatile("s_waitcnt lgkmcnt(0)" ::: "memory");
    }

    // ---- output: xyz then deform
    if (r_ < 4) {
        int mm = q*4 + r_;
        int p = pb + mm;
        out[p*3+0] = px[r_]; out[p*3+1] = py[r_]; out[p*3+2] = pz[r_];
        float* o9 = out + (size_t)N*3 + (size_t)p*9;
        #pragma unroll
        for (int j = 0; j < 9; ++j) o9[j] = defS[w][mm][j];
    }
}

extern "C" void kernel_launch(void* const* d_in, const int* in_sizes, int n_in,
                              void* d_out, int out_size, void* d_ws, size_t ws_size,
                              hipStream_t stream) {
    const float* code = (const float*)d_in[0];
    const float* pos  = (const float*)d_in[1];
    const float* t1   = (const float*)d_in[2];
    const float* t2   = (const float*)d_in[3];
    const float* W1   = (const float*)d_in[4];
    const float* b1   = (const float*)d_in[5];
    const float* W2   = (const float*)d_in[6];
    const float* b2   = (const float*)d_in[7];
    const float* W3   = (const float*)d_in[8];
    const float* b3   = (const float*)d_in[9];
    float* out = (float*)d_out;
    const int N = in_sizes[1] / 3;           // 131072
    const int blocks = N / PPB;              // 2048
    velwarp<<<blocks, 256, 0, stream>>>(code, pos, t1, t2, W1, b1, W2, b2, W3, b3, out, N);
}